// Round 9
// baseline (2422.843 us; speedup 1.0000x reference)
//
#include <hip/hip_runtime.h>

#define NN 1024
#define MM 1024
#define NB 16
#define BIGF 1.0e10f

typedef float f32x4 __attribute__((ext_vector_type(4)));

__device__ __forceinline__ float softmin3f(float a, float b, float c) {
  float mn = fminf(a, fminf(b, c));
  float s = __expf(mn - a) + __expf(mn - b) + __expf(mn - c);
  return mn - __logf(s);
}

// D[b,i,j] = (x[b,i] - y[j])^2 ; coalesced float4 writes
__global__ __launch_bounds__(256) void d_init_kernel(const float* __restrict__ x,
                                                     const float* __restrict__ y,
                                                     float* __restrict__ D) {
  size_t idx = ((size_t)blockIdx.x * blockDim.x + threadIdx.x) * 4;
  int j = (int)(idx & (MM - 1));
  size_t bi = idx >> 10;
  float xi = x[bi];
  const float4 yv = *reinterpret_cast<const float4*>(y + j);
  float t0 = xi - yv.x, t1 = xi - yv.y, t2 = xi - yv.z, t3 = xi - yv.w;
  float4 o;
  o.x = t0 * t0; o.y = t1 * t1; o.z = t2 * t2; o.w = t3 * t3;
  *reinterpret_cast<float4*>(D + idx) = o;
}

// R boundary: R[b,0,0]=0, R[b,0,j>=1]=BIG, R[b,i>=1,0]=BIG
__global__ __launch_bounds__(1024) void r_bound_kernel(float* __restrict__ R) {
  int b = blockIdx.x, t = threadIdx.x;
  float* Rb = R + (size_t)b * (NN + 1) * (MM + 1);
  Rb[t + 1] = BIGF;
  Rb[(size_t)(t + 1) * (MM + 1)] = BIGF;
  if (t == 0) Rb[0] = 0.0f;
}

// Forward DP: 256 threads; thread t owns rows r0..r0+3 (r0 = 4t+1).
// Per diag: rows 1..3 chain in registers; row 0's up-neighbor via parity-
// double-buffered LDS exch (1 read + 1 write). Carry identity supplies all
// diag-neighbors. Output staged in rv[4][16] registers, flushed as dword-
// aligned float4s per 16-diag block (fire-and-forget).
__global__ __launch_bounds__(256, 1) void sdtw_fwd(const float* __restrict__ x,
                                                   const float* __restrict__ y,
                                                   float* __restrict__ R,
                                                   float* __restrict__ score) {
  __shared__ float exch[2][257];
  const int b = blockIdx.x, t = threadIdx.x;
  for (int k = t; k < 2 * 257; k += 256) (&exch[0][0])[k] = BIGF;
  if (t == 0) exch[0][0] = 0.0f;  // R(0,0), read as up at d=1 -> dg at d=2
  const int r0 = 4 * t + 1;
  float* __restrict__ Rb = R + (size_t)b * (NN + 1) * (MM + 1);
  const float x0 = x[b * NN + 4 * t + 0];
  const float x1 = x[b * NN + 4 * t + 1];
  const float x2 = x[b * NN + 4 * t + 2];
  const float x3 = x[b * NN + 4 * t + 3];
  float p0 = BIGF, p1 = BIGF, p2 = BIGF, p3 = BIGF;  // prev-diag values
  float g0 = BIGF, g1 = BIGF, g2 = BIGF, g3 = BIGF;  // diag carries
  __syncthreads();
  for (int blk = 0; blk <= 128; ++blk) {
    const int d0 = blk << 4;
    float yB[20];
#pragma unroll
    for (int q = 0; q < 20; ++q) {
      const int yi = d0 - 4 * t - 5 + q;
      yB[q] = y[min(MM - 1, max(0, yi))];
    }
    float rv0[16], rv1[16], rv2[16], rv3[16];
#pragma unroll
    for (int p = 0; p < 16; ++p) {
      const int d = d0 + p;
      const int rp = (d & 1) ^ 1, wp = d & 1;
      const float up0 = exch[rp][t];  // R(r0-1, j0) ; slot 0 = row-0 boundary
      if (d == 1 && t == 0) exch[0][0] = BIGF;  // after the d=1 read: boundary
      float dv0 = x0 - yB[p + 3]; dv0 *= dv0;
      const float n0 = dv0 + softmin3f(g0, up0, p0);
      float dv1 = x1 - yB[p + 2]; dv1 *= dv1;
      const float n1 = dv1 + softmin3f(g1, p0, p1);
      float dv2 = x2 - yB[p + 1]; dv2 *= dv2;
      const float n2 = dv2 + softmin3f(g2, p1, p2);
      float dv3 = x3 - yB[p + 0]; dv3 *= dv3;
      const float n3 = dv3 + softmin3f(g3, p2, p3);
      g0 = up0; g1 = p0; g2 = p1; g3 = p2;  // carries use OLD prevs
      const int j0 = d - r0;
      const bool a0 = (j0 >= 1) && (j0 <= MM);
      const bool a1 = (j0 >= 2) && (j0 <= MM + 1);
      const bool a2 = (j0 >= 3) && (j0 <= MM + 2);
      const bool a3 = (j0 >= 4) && (j0 <= MM + 3);
      p0 = a0 ? n0 : p0;
      p1 = a1 ? n1 : p1;
      p2 = a2 ? n2 : p2;
      p3 = a3 ? n3 : p3;
      rv0[p] = n0; rv1[p] = n1; rv2[p] = n2; rv3[p] = n3;
      if (a3) exch[wp][t + 1] = n3;  // publish bottom row for thread t+1
      __syncthreads();
    }
    // flush: per row, 4 dword-aligned float4 groups (rv[4m+c] is col jm+c)
    auto fstore = [&](int ri, float (&rv)[16]) {
#pragma unroll
      for (int m = 0; m < 4; ++m) {
        const int jm = d0 + 4 * m - ri;
        if (jm >= 1 && jm + 3 <= MM) {
          *reinterpret_cast<float4*>(Rb + (size_t)ri * (MM + 1) + jm) =
              make_float4(rv[4 * m], rv[4 * m + 1], rv[4 * m + 2], rv[4 * m + 3]);
        } else if (jm + 3 >= 1 && jm <= MM) {
#pragma unroll
          for (int c = 0; c < 4; ++c) {
            const int jc = jm + c;
            if (jc >= 1 && jc <= MM) Rb[(size_t)ri * (MM + 1) + jc] = rv[4 * m + c];
          }
        }
      }
    };
    fstore(r0, rv0);
    fstore(r0 + 1, rv1);
    fstore(r0 + 2, rv2);
    fstore(r0 + 3, rv3);
  }
  if (t == 255) score[b] = p3;  // R[1024][1024]
}

// Backward: Rbar(i,j) = seed + E(i+1,j)e^{R(i+1,j)-R(i,j)-D(i+1,j)}
//  + E(i,j+1)e^{R(i,j+1)-R(i,j)-D(i,j+1)} + E(i+1,j+1)e^{R(i+1,j+1)-R(i,j)-D(i+1,j+1)}
// Same 4-rows/thread layout, reverse sweep. Row 3's down-neighbor via parity
// LDS exch pair (E,R) from thread t+1's row 0; everything else registers.
// R ring double-buffered in registers; next block's loads issued at block top,
// hidden under the 16 steps. E overwrites the ring in place; (0,-BIG) inits
// make all invalid exp-terms exactly 0 (no masks in the formula).
__global__ __launch_bounds__(256, 1) void sdtw_bwd(const float* __restrict__ x,
                                                   const float* __restrict__ y,
                                                   const float* __restrict__ R,
                                                   float* __restrict__ E) {
  __shared__ float eex[2][257];
  __shared__ float rex[2][257];
  const int b = blockIdx.x, t = threadIdx.x;
  for (int k = t; k < 2 * 257; k += 256) {
    (&eex[0][0])[k] = 0.0f;
    (&rex[0][0])[k] = -BIGF;
  }
  const int r0 = 4 * t + 1;
  const float* __restrict__ Rb = R + (size_t)b * (NN + 1) * (MM + 1);
  float* __restrict__ Eb = E + (size_t)b * (size_t)NN * MM;
  const float x0 = x[b * NN + 4 * t + 0];              // x(r0)
  const float x1 = x[b * NN + 4 * t + 1];
  const float x2 = x[b * NN + 4 * t + 2];
  const float x3 = x[b * NN + 4 * t + 3];              // x(r3)
  const float x4 = x[b * NN + min(NN - 1, 4 * t + 4)]; // x(r3+1), clamped
  float pE0 = 0.f, pE1 = 0.f, pE2 = 0.f, pE3 = 0.f;
  float pR0 = -BIGF, pR1 = -BIGF, pR2 = -BIGF, pR3 = -BIGF;
  float gE0 = 0.f, gE1 = 0.f, gE2 = 0.f, gE3 = 0.f;
  float gR0 = -BIGF, gR1 = -BIGF, gR2 = -BIGF, gR3 = -BIGF;
  float rgA[4][16], rgB[4][16];

  auto loadRing = [&](float (&dst)[4][16], int kkn) {
    const int d0n = kkn << 4;
#pragma unroll
    for (int k = 0; k < 4; ++k) {
      const int ri = r0 + k;
      const float* rowp = Rb + (size_t)ri * (MM + 1);
#pragma unroll
      for (int m = 0; m < 4; ++m) {
        const int jm = d0n + 4 * m - ri;
        if (jm >= 0 && jm + 3 <= MM) {
          const float4 v = *reinterpret_cast<const float4*>(rowp + jm);
          dst[k][4 * m] = v.x; dst[k][4 * m + 1] = v.y;
          dst[k][4 * m + 2] = v.z; dst[k][4 * m + 3] = v.w;
        } else {
#pragma unroll
          for (int c = 0; c < 4; ++c) {
            const int jc = min(MM, max(0, jm + c));
            dst[k][4 * m + c] = rowp[jc];  // garbage only for inactive cells
          }
        }
      }
    }
  };

  auto estore = [&](int d0, int ri, float (&ev)[16]) {
    float* erow = Eb + (size_t)(ri - 1) * MM;
#pragma unroll
    for (int m = 0; m < 4; ++m) {
      const int jm = d0 + 4 * m - ri;
      if (jm >= 1 && jm + 3 <= MM) {
        f32x4 v;
        v[0] = ev[4 * m]; v[1] = ev[4 * m + 1];
        v[2] = ev[4 * m + 2]; v[3] = ev[4 * m + 3];
        const float* pp = erow + (jm - 1);
        asm volatile("global_store_dwordx4 %0, %1, off" ::"v"(pp), "v"(v) : "memory");
      } else if (jm + 3 >= 1 && jm <= MM) {
#pragma unroll
        for (int c = 0; c < 4; ++c) {
          const int jc = jm + c;
          if (jc >= 1 && jc <= MM) erow[jc - 1] = ev[4 * m + c];
        }
      }
    }
  };

  auto body = [&](float (&cur)[4][16], float (&nxt)[4][16], int kk) {
    const int d0 = kk << 4;
    if (kk > 0) loadRing(nxt, kk - 1);  // in flight under the 16 steps
    float yB[20];
#pragma unroll
    for (int q = 0; q < 20; ++q) {
      const int yi = d0 - 4 * t - 5 + q;
      yB[q] = y[min(MM - 1, max(0, yi))];
    }
#pragma unroll
    for (int p = 0; p < 16; ++p) {
      const int s = 15 - p;
      const int d = d0 + s;
      const int rp = (d & 1) ^ 1, wp = d & 1;
      const float exE = eex[rp][t + 1];  // E(r3+1, j3) from thread t+1 row 0
      const float exR = rex[rp][t + 1];
      // k=3 (rows bottom-up; all dn/dg/rt terms use OLD state)
      const float r3v = cur[3][s];
      float A1 = x4 - yB[s + 0]; A1 *= A1;
      float A2 = x3 - yB[s + 1]; A2 *= A2;
      float A3 = x4 - yB[s + 1]; A3 *= A3;
      float e3 = exE * __expf(exR - r3v - A1) + pE3 * __expf(pR3 - r3v - A2) +
                 gE3 * __expf(gR3 - r3v - A3);
      if (t == 255 && d == 2048) e3 += 1.0f;  // seed at (N, M)
      // k=2
      const float r2v = cur[2][s];
      float B1 = x3 - yB[s + 1]; B1 *= B1;
      float B2 = x2 - yB[s + 2]; B2 *= B2;
      float B3 = x3 - yB[s + 2]; B3 *= B3;
      float e2 = pE3 * __expf(pR3 - r2v - B1) + pE2 * __expf(pR2 - r2v - B2) +
                 gE2 * __expf(gR2 - r2v - B3);
      // k=1
      const float r1v = cur[1][s];
      float C1 = x2 - yB[s + 2]; C1 *= C1;
      float C2 = x1 - yB[s + 3]; C2 *= C2;
      float C3 = x2 - yB[s + 3]; C3 *= C3;
      float e1 = pE2 * __expf(pR2 - r1v - C1) + pE1 * __expf(pR1 - r1v - C2) +
                 gE1 * __expf(gR1 - r1v - C3);
      // k=0
      const float r0v = cur[0][s];
      float D1 = x1 - yB[s + 3]; D1 *= D1;
      float D2 = x0 - yB[s + 4]; D2 *= D2;
      float D3 = x1 - yB[s + 4]; D3 *= D3;
      float e0 = pE1 * __expf(pR1 - r0v - D1) + pE0 * __expf(pR0 - r0v - D2) +
                 gE0 * __expf(gR0 - r0v - D3);
      // diag carries (old values)
      gE3 = exE; gR3 = exR;
      gE2 = pE3; gR2 = pR3;
      gE1 = pE2; gR1 = pR2;
      gE0 = pE1; gR0 = pR1;
      // masked updates (j_k = j0 - k)
      const int j0 = d - r0;
      const bool a0 = (j0 >= 1) && (j0 <= MM);
      const bool a1 = (j0 >= 2) && (j0 <= MM + 1);
      const bool a2 = (j0 >= 3) && (j0 <= MM + 2);
      const bool a3 = (j0 >= 4) && (j0 <= MM + 3);
      pE0 = a0 ? e0 : pE0;  pR0 = a0 ? r0v : pR0;
      pE1 = a1 ? e1 : pE1;  pR1 = a1 ? r1v : pR1;
      pE2 = a2 ? e2 : pE2;  pR2 = a2 ? r2v : pR2;
      pE3 = a3 ? e3 : pE3;  pR3 = a3 ? r3v : pR3;
      cur[0][s] = e0; cur[1][s] = e1; cur[2][s] = e2; cur[3][s] = e3;
      if (a0) { eex[wp][t] = e0; rex[wp][t] = r0v; }  // publish top row
      __syncthreads();
    }
    estore(d0, r0, cur[0]);
    estore(d0, r0 + 1, cur[1]);
    estore(d0, r0 + 2, cur[2]);
    estore(d0, r0 + 3, cur[3]);
  };

  loadRing(rgA, 128);
  __syncthreads();
  body(rgA, rgB, 128);
  for (int kk = 127; kk >= 1; kk -= 2) {
    body(rgB, rgA, kk);
    body(rgA, rgB, kk - 1);
  }
}

extern "C" void kernel_launch(void* const* d_in, const int* in_sizes, int n_in,
                              void* d_out, int out_size, void* d_ws, size_t ws_size,
                              hipStream_t stream) {
  const float* x = (const float*)d_in[0];  // [16, 1024]
  const float* y = (const float*)d_in[1];  // [1024]
  float* out = (float*)d_out;
  float* score = out;                               // [16]
  float* D = out + NB;                              // [16,1024,1024]
  float* R = D + (size_t)NB * NN * MM;              // [16,1025,1025]
  float* E = R + (size_t)NB * (NN + 1) * (MM + 1);  // [16,1024,1024]

  hipLaunchKernelGGL(d_init_kernel, dim3((NB * NN * MM) / (256 * 4)), dim3(256), 0, stream,
                     x, y, D);
  hipLaunchKernelGGL(r_bound_kernel, dim3(NB), dim3(1024), 0, stream, R);
  hipLaunchKernelGGL(sdtw_fwd, dim3(NB), dim3(256), 0, stream, x, y, R, score);
  hipLaunchKernelGGL(sdtw_bwd, dim3(NB), dim3(256), 0, stream, x, y, R, E);
}

// Round 10
// 1468.930 us; speedup vs baseline: 1.6494x; 1.6494x over previous
//
#include <hip/hip_runtime.h>

#define NN 1024
#define MM 1024
#define NB 16
#define BIGF 1.0e10f
#define TP 17                       // bwd tile pad
#define NW 8                        // fwd: waves per workgroup
#define OFS 5                       // fwd: interval offset between waves
#define CW 16                       // fwd: steps per interval
#define NA 68                       // fwd: active intervals per wave
#define NGI (OFS * (NW - 1) + NA)   // fwd: 103 global intervals

typedef float f32x4 __attribute__((ext_vector_type(4)));

// softmin3 with the always-one term elided: one of exp(mn-*) is exp(0)=1.
// s = 1 + exp(mn-med) + exp(mn-max): 2 exp + 1 log (was 3 exp + 1 log).
__device__ __forceinline__ float softmin3f(float a, float b, float c) {
  const float mn = fminf(a, fminf(b, c));
  const float mx = fmaxf(a, fmaxf(b, c));
  const float md = __builtin_amdgcn_fmed3f(a, b, c);
  const float s = 1.0f + __expf(mn - md) + __expf(mn - mx);
  return mn - __logf(s);
}

// D[b,i,j] = (x[b,i] - y[j])^2 ; coalesced float4 writes
__global__ __launch_bounds__(256) void d_init_kernel(const float* __restrict__ x,
                                                     const float* __restrict__ y,
                                                     float* __restrict__ D) {
  size_t idx = ((size_t)blockIdx.x * blockDim.x + threadIdx.x) * 4;
  int j = (int)(idx & (MM - 1));
  size_t bi = idx >> 10;
  float xi = x[bi];
  const float4 yv = *reinterpret_cast<const float4*>(y + j);
  float t0 = xi - yv.x, t1 = xi - yv.y, t2 = xi - yv.z, t3 = xi - yv.w;
  float4 o;
  o.x = t0 * t0; o.y = t1 * t1; o.z = t2 * t2; o.w = t3 * t3;
  *reinterpret_cast<float4*>(D + idx) = o;
}

// R boundary: R[b,0,0]=0, R[b,0,j>=1]=BIG, R[b,i>=1,0]=BIG
__global__ __launch_bounds__(1024) void r_bound_kernel(float* __restrict__ R) {
  int b = blockIdx.x, t = threadIdx.x;
  float* Rb = R + (size_t)b * (NN + 1) * (MM + 1);
  Rb[t + 1] = BIGF;
  Rb[(size_t)(t + 1) * (MM + 1)] = BIGF;
  if (t == 0) Rb[0] = 0.0f;
}

// ---------------- forward (round-5 structure, measured best) ----------------
// Wave w owns rows 128w+1..128w+128; lane l owns i1=128w+2l+1, i2=i1+1.
// Lane l at step s computes col j = s - l. Neighbors via __shfl_up; strip
// boundary row via LDS ring (wave w-1 runs OFS intervals ahead). Output R
// staged per 16-step window in a per-wave parallelogram LDS tile
// (addr = 33*l + {0,16} + p, odd lane stride -> conflict-free), then
// cooperatively stored coalesced.
__global__ __launch_bounds__(512) void sdtw_fwd(const float* __restrict__ x,
                                                const float* __restrict__ y,
                                                float* __restrict__ R,
                                                float* __restrict__ score) {
  __shared__ float ylds[MM];
  __shared__ float tile[NW][2112];
  __shared__ float ringR[NW][128];
  const int b = blockIdx.x, t = threadIdx.x;
  const int w = t >> 6, l = t & 63;
  float* __restrict__ Rb = R + (size_t)b * (NN + 1) * (MM + 1);
  for (int k = t; k < MM; k += 512) ylds[k] = y[k];
  const int i1 = 128 * w + 2 * l + 1;
  const float x1 = x[b * NN + i1 - 1];
  const float x2 = x[b * NN + i1];
  float* tl = &tile[w][33 * l];
  const int wm1 = (w > 0) ? (w - 1) : 0;
  const bool L0 = (l == 0), W0 = (w == 0);
  const bool pub = (l == 63) && (w < NW - 1);
  float c1 = BIGF, c2 = BIGF, m1 = BIGF, m2 = BIGF, ringPrev = BIGF;
  __syncthreads();
  for (int G = 0; G < NGI; ++G) {
    const int a = G - OFS * w;
    if (a >= 0 && a < NA) {
      const int s0 = a * CW;
#pragma unroll 4
      for (int p = 0; p < CW; ++p) {
        const int s = s0 + p;
        const int j = s - l;
        const bool act = (j >= 1) && (j <= MM);
        float up = __shfl_up(m1, 1);   // R(i1-1, j)
        float dg = __shfl_up(m2, 1);   // R(i1-1, j-1)
        const float rc = ringR[wm1][j & 127];
        if (L0) {
          up = W0 ? BIGF : rc;
          dg = W0 ? ((j == 1) ? 0.0f : BIGF) : ringPrev;
        }
        ringPrev = act ? rc : ringPrev;
        const float yv = ylds[act ? (j - 1) : 0];
        float dv1 = x1 - yv; dv1 *= dv1;
        const float r1 = dv1 + softmin3f(dg, up, c1);
        float dv2 = x2 - yv; dv2 *= dv2;
        const float r2 = dv2 + softmin3f(c1, r1, c2);
        tl[p] = r1;
        tl[16 + p] = r2;
        if (pub && act) ringR[w][j & 127] = r2;
        m2 = act ? m1 : m2;
        m1 = act ? r2 : m1;
        c1 = act ? r1 : c1;
        c2 = act ? r2 : c2;
      }
      __builtin_amdgcn_wave_barrier();
      // cooperative coalesced store of window a (own wave's tile only)
#pragma unroll
      for (int g = 0; g < 32; ++g) {
        const int rr = 4 * g + (l >> 4);
        const int sl = l & 15;
        const int col = s0 + sl - (rr >> 1);
        const float v = tile[w][rr * 16 + (rr >> 1) + sl];
        if (col >= 1 && col <= MM)
          Rb[(size_t)(128 * w + 1 + rr) * (MM + 1) + col] = v;
      }
    }
    __syncthreads();
  }
  if (w == NW - 1 && l == 63) score[b] = m1;  // R[1024][1024]
}

// ---------------- backward (round-4 structure, measured best) ---------------
// Rbar(i,j) = seed + E_dn*exp(R_dn-rij-D_dn) + E_rt*exp(R_rt-rij-D_rt)
//                  + E_dg*exp(R_dg-rij-D_dg); E[i-1][j-1] = Rbar(i,j).
// Single LDS tile holds R of the current 16-diag block; each cell's slot is
// overwritten in place with the computed E; block end: coop-store E, coop-load
// next R block into the same slots.
__global__ __launch_bounds__(1024) void sdtw_bwd(const float* __restrict__ x,
                                                 const float* __restrict__ y,
                                                 const float* __restrict__ R,
                                                 float* __restrict__ E) {
  __shared__ float ylds[MM];
  __shared__ float rbx[4][NN + 2];
  __shared__ float ebx[4][NN + 2];
  __shared__ float tile[NN][TP];
  const int b = blockIdx.x, t = threadIdx.x;
  const int i = t + 1;
  const float* __restrict__ Rb = R + (size_t)b * (NN + 1) * (MM + 1);
  float* __restrict__ Eb = E + (size_t)b * (size_t)NN * MM;
  ylds[t] = y[t];
#pragma unroll
  for (int q = 0; q < 4; ++q) { rbx[q][i] = -BIGF; ebx[q][i] = 0.0f; }
  if (t == NN - 1) {
#pragma unroll
    for (int q = 0; q < 4; ++q) { rbx[q][NN + 1] = -BIGF; ebx[q][NN + 1] = 0.0f; }
  }
  const float xi = x[b * NN + t];                              // X(i)
  const float xi1 = x[b * NN + ((t + 1 < NN) ? (t + 1) : t)];  // X(i+1)
  const bool idn = (i + 1 <= NN);
  const bool seedrow = (i == NN);
  float rt_e = 0.0f, rt_r = -BIGF;    // (i, j+1) carries
  float dgn_e = 0.0f, dgn_r = -BIGF;  // (i+1, j+1) carries
  // prologue: coop-load R tile for block K=128
#pragma unroll
  for (int pass = 0; pass < 4; ++pass) {
    const int row = (pass << 8) + (t >> 2);
    const int ir = row + 1;
    const int c4 = (t & 3) << 2;
    const int jb2 = (128 << 4) - ir + c4;
    if (jb2 >= 1 && jb2 + 3 <= MM) {
      const float4 v = *reinterpret_cast<const float4*>(Rb + (size_t)ir * (MM + 1) + jb2);
      tile[row][c4] = v.x; tile[row][c4 + 1] = v.y;
      tile[row][c4 + 2] = v.z; tile[row][c4 + 3] = v.w;
    } else {
#pragma unroll
      for (int c = 0; c < 4; ++c) {
        const int jc = jb2 + c;
        tile[row][c4 + c] =
            (jc >= 1 && jc <= MM) ? Rb[(size_t)ir * (MM + 1) + jc] : -BIGF;
      }
    }
  }
  __syncthreads();
  float yj = ylds[min(MM - 1, max(0, 2063 - i))];  // y[j] rotation seed

  for (int K = 128; K >= 0; --K) {
    const int d0 = K << 4;
#pragma unroll
    for (int p = 0; p < 16; ++p) {
      const int s = 15 - p;  // descending d within block
      const int d = d0 + s;
      const int j = d - i;
      const bool act = (j >= 1) && (j <= MM);
      const bool vrt = (j < MM);
      const float dn_r = rbx[(s + 1) & 3][i + 1];  // (i+1, j) at diag d+1
      const float dn_e = ebx[(s + 1) & 3][i + 1];
      const float yjm1 = ylds[min(MM - 1, max(0, j - 1))];
      const float rij = tile[t][s];
      float d1 = xi1 - yjm1; d1 *= d1;  // D(i+1, j)
      float d2 = xi - yj;    d2 *= d2;  // D(i,   j+1)
      float d3 = xi1 - yj;   d3 *= d3;  // D(i+1, j+1)
      const float a1 = idn ? (dn_r - rij - d1) : -BIGF;
      const float a2 = vrt ? (rt_r - rij - d2) : -BIGF;
      const float a3 = (idn && vrt) ? (dgn_r - rij - d3) : -BIGF;
      float acc = dn_e * __expf(a1) + rt_e * __expf(a2) + dgn_e * __expf(a3);
      if (seedrow && j == MM) acc += 1.0f;
      rbx[s & 3][i] = act ? rij : -BIGF;
      ebx[s & 3][i] = act ? acc : 0.0f;
      tile[t][s] = act ? acc : 0.0f;  // in-place E
      rt_e = act ? acc : 0.0f;
      rt_r = act ? rij : -BIGF;
      dgn_e = dn_e; dgn_r = dn_r;
      yj = yjm1;
      __syncthreads();
    }
    // coop: store E tile, then load R tile for block K-1 into same slots
#pragma unroll
    for (int pass = 0; pass < 4; ++pass) {
      const int row = (pass << 8) + (t >> 2);
      const int ir = row + 1;
      const int c4 = (t & 3) << 2;
      const int jb2 = d0 - ir + c4;
      float fv[4];
#pragma unroll
      for (int c = 0; c < 4; ++c) fv[c] = tile[row][c4 + c];
      if (jb2 >= 1 && jb2 + 3 <= MM) {
        f32x4 v;
        v[0] = fv[0]; v[1] = fv[1]; v[2] = fv[2]; v[3] = fv[3];
        const float* pp = Eb + (size_t)row * MM + (jb2 - 1);
        asm volatile("global_store_dwordx4 %0, %1, off" ::"v"(pp), "v"(v) : "memory");
      } else if (jb2 + 3 >= 1 && jb2 <= MM) {
#pragma unroll
        for (int c = 0; c < 4; ++c) {
          const int jc = jb2 + c;
          if (jc >= 1 && jc <= MM) Eb[(size_t)row * MM + (jc - 1)] = fv[c];
        }
      }
      const int jn = jb2 - 16;  // next block window
      if (jn >= 1 && jn + 3 <= MM) {
        const float4 v = *reinterpret_cast<const float4*>(Rb + (size_t)ir * (MM + 1) + jn);
        tile[row][c4] = v.x; tile[row][c4 + 1] = v.y;
        tile[row][c4 + 2] = v.z; tile[row][c4 + 3] = v.w;
      } else {
#pragma unroll
        for (int c = 0; c < 4; ++c) {
          const int jc = jn + c;
          tile[row][c4 + c] =
              (jc >= 1 && jc <= MM) ? Rb[(size_t)ir * (MM + 1) + jc] : -BIGF;
        }
      }
    }
    __syncthreads();
  }
}

extern "C" void kernel_launch(void* const* d_in, const int* in_sizes, int n_in,
                              void* d_out, int out_size, void* d_ws, size_t ws_size,
                              hipStream_t stream) {
  const float* x = (const float*)d_in[0];  // [16, 1024]
  const float* y = (const float*)d_in[1];  // [1024]
  float* out = (float*)d_out;
  float* score = out;                               // [16]
  float* D = out + NB;                              // [16,1024,1024]
  float* R = D + (size_t)NB * NN * MM;              // [16,1025,1025]
  float* E = R + (size_t)NB * (NN + 1) * (MM + 1);  // [16,1024,1024]

  hipLaunchKernelGGL(d_init_kernel, dim3((NB * NN * MM) / (256 * 4)), dim3(256), 0, stream,
                     x, y, D);
  hipLaunchKernelGGL(r_bound_kernel, dim3(NB), dim3(1024), 0, stream, R);
  hipLaunchKernelGGL(sdtw_fwd, dim3(NB), dim3(512), 0, stream, x, y, R, score);
  hipLaunchKernelGGL(sdtw_bwd, dim3(NB), dim3(1024), 0, stream, x, y, R, E);
}

// Round 11
// 1411.307 us; speedup vs baseline: 1.7167x; 1.0408x over previous
//
#include <hip/hip_runtime.h>

#define NN 1024
#define MM 1024
#define NB 16
#define BIGF 1.0e10f
#define TP 17                       // bwd tile pad
#define NW 8                        // fwd: waves per workgroup
#define OFS 5                       // fwd: interval offset between waves
#define CW 16                       // fwd: steps per interval
#define NA 68                       // fwd: active intervals per wave
#define NGI (OFS * (NW - 1) + NA)   // fwd: 103 global intervals

typedef float f32x4 __attribute__((ext_vector_type(4)));

// softmin3 with the always-one term elided: one of exp(mn-*) is exp(0)=1.
__device__ __forceinline__ float softmin3f(float a, float b, float c) {
  const float mn = fminf(a, fminf(b, c));
  const float mx = fmaxf(a, fmaxf(b, c));
  const float md = __builtin_amdgcn_fmed3f(a, b, c);
  const float s = 1.0f + __expf(mn - md) + __expf(mn - mx);
  return mn - __logf(s);
}

// D[b,i,j] = (x[b,i] - y[j])^2 ; coalesced float4 writes
__global__ __launch_bounds__(256) void d_init_kernel(const float* __restrict__ x,
                                                     const float* __restrict__ y,
                                                     float* __restrict__ D) {
  size_t idx = ((size_t)blockIdx.x * blockDim.x + threadIdx.x) * 4;
  int j = (int)(idx & (MM - 1));
  size_t bi = idx >> 10;
  float xi = x[bi];
  const float4 yv = *reinterpret_cast<const float4*>(y + j);
  float t0 = xi - yv.x, t1 = xi - yv.y, t2 = xi - yv.z, t3 = xi - yv.w;
  float4 o;
  o.x = t0 * t0; o.y = t1 * t1; o.z = t2 * t2; o.w = t3 * t3;
  *reinterpret_cast<float4*>(D + idx) = o;
}

// R boundary: R[b,0,0]=0, R[b,0,j>=1]=BIG, R[b,i>=1,0]=BIG
__global__ __launch_bounds__(1024) void r_bound_kernel(float* __restrict__ R) {
  int b = blockIdx.x, t = threadIdx.x;
  float* Rb = R + (size_t)b * (NN + 1) * (MM + 1);
  Rb[t + 1] = BIGF;
  Rb[(size_t)(t + 1) * (MM + 1)] = BIGF;
  if (t == 0) Rb[0] = 0.0f;
}

// ---------------- forward (round-5 structure; padded-y) ---------------------
__global__ __launch_bounds__(512) void sdtw_fwd(const float* __restrict__ x,
                                                const float* __restrict__ y,
                                                float* __restrict__ R,
                                                float* __restrict__ score) {
  __shared__ float ypad[1152];  // ypad[k] = y[k-64], zeros outside
  __shared__ float tile[NW][2112];
  __shared__ float ringR[NW][128];
  const int b = blockIdx.x, t = threadIdx.x;
  const int w = t >> 6, l = t & 63;
  float* __restrict__ Rb = R + (size_t)b * (NN + 1) * (MM + 1);
  for (int k = t; k < 1152; k += 512)
    ypad[k] = (k >= 64 && k < 64 + MM) ? y[k - 64] : 0.0f;
  const int i1 = 128 * w + 2 * l + 1;
  const float x1 = x[b * NN + i1 - 1];
  const float x2 = x[b * NN + i1];
  float* tl = &tile[w][33 * l];
  const int wm1 = (w > 0) ? (w - 1) : 0;
  const bool L0 = (l == 0), W0 = (w == 0);
  const bool pub = (l == 63) && (w < NW - 1);
  float c1 = BIGF, c2 = BIGF, m1 = BIGF, m2 = BIGF, ringPrev = BIGF;
  __syncthreads();
  for (int G = 0; G < NGI; ++G) {
    const int a = G - OFS * w;
    if (a >= 0 && a < NA) {
      const int s0 = a * CW;
#pragma unroll 4
      for (int p = 0; p < CW; ++p) {
        const int s = s0 + p;
        const int j = s - l;
        const bool act = (j >= 1) && (j <= MM);
        float up = __shfl_up(m1, 1);   // R(i1-1, j)
        float dg = __shfl_up(m2, 1);   // R(i1-1, j-1)
        const float rc = ringR[wm1][j & 127];
        if (L0) {
          up = W0 ? BIGF : rc;
          dg = W0 ? ((j == 1) ? 0.0f : BIGF) : ringPrev;
        }
        ringPrev = act ? rc : ringPrev;
        const float yv = ypad[j + 63];  // y[j-1]; pad-zero when inactive
        float dv1 = x1 - yv; dv1 *= dv1;
        const float r1 = dv1 + softmin3f(dg, up, c1);
        float dv2 = x2 - yv; dv2 *= dv2;
        const float r2 = dv2 + softmin3f(c1, r1, c2);
        tl[p] = r1;
        tl[16 + p] = r2;
        if (pub && act) ringR[w][j & 127] = r2;
        m2 = act ? m1 : m2;
        m1 = act ? r2 : m1;
        c1 = act ? r1 : c1;
        c2 = act ? r2 : c2;
      }
      __builtin_amdgcn_wave_barrier();
      // cooperative coalesced store of window a (own wave's tile only)
#pragma unroll
      for (int g = 0; g < 32; ++g) {
        const int rr = 4 * g + (l >> 4);
        const int sl = l & 15;
        const int col = s0 + sl - (rr >> 1);
        const float v = tile[w][rr * 16 + (rr >> 1) + sl];
        if (col >= 1 && col <= MM)
          Rb[(size_t)(128 * w + 1 + rr) * (MM + 1) + col] = v;
      }
    }
    __syncthreads();
  }
  if (w == NW - 1 && l == 63) score[b] = m1;  // R[1024][1024]
}

// ---------------- backward (round-4 structure; mask-elided, padded-y) -------
// Guard selects removed: invalid neighbors always carry (E=0, R=-BIG) via
// pads and act-masked carries -> exp term underflows to 0; any 0*inf NaN
// occurs only in inactive cells whose results are discarded by act-selects.
__global__ __launch_bounds__(1024) void sdtw_bwd(const float* __restrict__ x,
                                                 const float* __restrict__ y,
                                                 const float* __restrict__ R,
                                                 float* __restrict__ E) {
  __shared__ float ypad[3088];  // ypad[k] = y[k-1025], zeros outside
  __shared__ float rbx[4][NN + 2];
  __shared__ float ebx[4][NN + 2];
  __shared__ float tile[NN][TP];
  const int b = blockIdx.x, t = threadIdx.x;
  const int i = t + 1;
  const float* __restrict__ Rb = R + (size_t)b * (NN + 1) * (MM + 1);
  float* __restrict__ Eb = E + (size_t)b * (size_t)NN * MM;
  for (int k = t; k < 3088; k += 1024)
    ypad[k] = (k >= 1025 && k < 1025 + MM) ? y[k - 1025] : 0.0f;
#pragma unroll
  for (int q = 0; q < 4; ++q) { rbx[q][i] = -BIGF; ebx[q][i] = 0.0f; }
  if (t == NN - 1) {
#pragma unroll
    for (int q = 0; q < 4; ++q) { rbx[q][NN + 1] = -BIGF; ebx[q][NN + 1] = 0.0f; }
  }
  const float xi = x[b * NN + t];                              // X(i)
  const float xi1 = x[b * NN + ((t + 1 < NN) ? (t + 1) : t)];  // X(i+1)
  const bool seedrow = (i == NN);
  float rt_e = 0.0f, rt_r = -BIGF;    // (i, j+1) carries
  float dgn_e = 0.0f, dgn_r = -BIGF;  // (i+1, j+1) carries
  // prologue: coop-load R tile for block K=128
#pragma unroll
  for (int pass = 0; pass < 4; ++pass) {
    const int row = (pass << 8) + (t >> 2);
    const int ir = row + 1;
    const int c4 = (t & 3) << 2;
    const int jb2 = (128 << 4) - ir + c4;
    if (jb2 >= 1 && jb2 + 3 <= MM) {
      const float4 v = *reinterpret_cast<const float4*>(Rb + (size_t)ir * (MM + 1) + jb2);
      tile[row][c4] = v.x; tile[row][c4 + 1] = v.y;
      tile[row][c4 + 2] = v.z; tile[row][c4 + 3] = v.w;
    } else {
#pragma unroll
      for (int c = 0; c < 4; ++c) {
        const int jc = jb2 + c;
        tile[row][c4 + c] =
            (jc >= 1 && jc <= MM) ? Rb[(size_t)ir * (MM + 1) + jc] : -BIGF;
      }
    }
  }
  __syncthreads();
  float yj = ypad[3088 - i];  // y[j] seed at d=2063 (j = 2063 - i)

  for (int K = 128; K >= 0; --K) {
    const int d0 = K << 4;
#pragma unroll
    for (int p = 0; p < 16; ++p) {
      const int s = 15 - p;  // descending d within block
      const int d = d0 + s;
      const int j = d - i;
      const bool act = (j >= 1) && (j <= MM);
      const float dn_r = rbx[(s + 1) & 3][i + 1];  // (i+1, j) at diag d+1
      const float dn_e = ebx[(s + 1) & 3][i + 1];
      const float yjm1 = ypad[j + 1024];           // y[j-1], pad-zero outside
      const float rij = tile[t][s];
      float d1 = xi1 - yjm1; d1 *= d1;  // D(i+1, j)
      float d2 = xi - yj;    d2 *= d2;  // D(i,   j+1)
      float d3 = xi1 - yj;   d3 *= d3;  // D(i+1, j+1)
      const float a1 = dn_r - rij - d1;
      const float a2 = rt_r - rij - d2;
      const float a3 = dgn_r - rij - d3;
      float acc = dn_e * __expf(a1) + rt_e * __expf(a2) + dgn_e * __expf(a3);
      if (seedrow && j == MM) acc += 1.0f;
      rbx[s & 3][i] = act ? rij : -BIGF;
      ebx[s & 3][i] = act ? acc : 0.0f;
      tile[t][s] = act ? acc : 0.0f;  // in-place E
      rt_e = act ? acc : 0.0f;
      rt_r = act ? rij : -BIGF;
      dgn_e = dn_e; dgn_r = dn_r;
      yj = yjm1;
      __syncthreads();
    }
    // coop: store E tile, then load R tile for block K-1 into same slots
#pragma unroll
    for (int pass = 0; pass < 4; ++pass) {
      const int row = (pass << 8) + (t >> 2);
      const int ir = row + 1;
      const int c4 = (t & 3) << 2;
      const int jb2 = d0 - ir + c4;
      float fv[4];
#pragma unroll
      for (int c = 0; c < 4; ++c) fv[c] = tile[row][c4 + c];
      if (jb2 >= 1 && jb2 + 3 <= MM) {
        f32x4 v;
        v[0] = fv[0]; v[1] = fv[1]; v[2] = fv[2]; v[3] = fv[3];
        const float* pp = Eb + (size_t)row * MM + (jb2 - 1);
        asm volatile("global_store_dwordx4 %0, %1, off" ::"v"(pp), "v"(v) : "memory");
      } else if (jb2 + 3 >= 1 && jb2 <= MM) {
#pragma unroll
        for (int c = 0; c < 4; ++c) {
          const int jc = jb2 + c;
          if (jc >= 1 && jc <= MM) Eb[(size_t)row * MM + (jc - 1)] = fv[c];
        }
      }
      const int jn = jb2 - 16;  // next block window
      if (jn >= 1 && jn + 3 <= MM) {
        const float4 v = *reinterpret_cast<const float4*>(Rb + (size_t)ir * (MM + 1) + jn);
        tile[row][c4] = v.x; tile[row][c4 + 1] = v.y;
        tile[row][c4 + 2] = v.z; tile[row][c4 + 3] = v.w;
      } else {
#pragma unroll
        for (int c = 0; c < 4; ++c) {
          const int jc = jn + c;
          tile[row][c4 + c] =
              (jc >= 1 && jc <= MM) ? Rb[(size_t)ir * (MM + 1) + jc] : -BIGF;
        }
      }
    }
    __syncthreads();
  }
}

extern "C" void kernel_launch(void* const* d_in, const int* in_sizes, int n_in,
                              void* d_out, int out_size, void* d_ws, size_t ws_size,
                              hipStream_t stream) {
  const float* x = (const float*)d_in[0];  // [16, 1024]
  const float* y = (const float*)d_in[1];  // [1024]
  float* out = (float*)d_out;
  float* score = out;                               // [16]
  float* D = out + NB;                              // [16,1024,1024]
  float* R = D + (size_t)NB * NN * MM;              // [16,1025,1025]
  float* E = R + (size_t)NB * (NN + 1) * (MM + 1);  // [16,1024,1024]

  hipLaunchKernelGGL(d_init_kernel, dim3((NB * NN * MM) / (256 * 4)), dim3(256), 0, stream,
                     x, y, D);
  hipLaunchKernelGGL(r_bound_kernel, dim3(NB), dim3(1024), 0, stream, R);
  hipLaunchKernelGGL(sdtw_fwd, dim3(NB), dim3(512), 0, stream, x, y, R, score);
  hipLaunchKernelGGL(sdtw_bwd, dim3(NB), dim3(1024), 0, stream, x, y, R, E);
}